// Round 1
// baseline (1412.186 us; speedup 1.0000x reference)
//
#include <hip/hip_runtime.h>
#include <stdint.h>

#define T_TOK 8192
#define D_DIM 1024
#define F_DIM 4096
#define E_NUM 8
#define RCAP  17408   // 136 * 128 >= 16384 + 8*127 (per-expert 128-aligned regions)
#define MT    136

typedef __bf16 bf16;
typedef __bf16 bf16x8 __attribute__((ext_vector_type(8)));
typedef float  f32x4  __attribute__((ext_vector_type(4)));

typedef const __attribute__((address_space(1))) void* gptr1;
typedef __attribute__((address_space(3))) void* lptr3;

__device__ __forceinline__ void gload_lds16(const void* g, void* l) {
    // async global->LDS DMA, 16B/lane; LDS dest = wave-uniform base + lane*16
    __builtin_amdgcn_global_load_lds((gptr1)g, (lptr3)l, 16, 0, 0);
}

__device__ __forceinline__ unsigned short f2b(float f) {
    // fp32 -> bf16 round-to-nearest-even
    uint32_t u = __float_as_uint(f);
    u = (u + 0x7FFFu + ((u >> 16) & 1u)) >> 16;
    return (unsigned short)u;
}

// ---------------------------------------------------------------------------
// Transpose-convert: src fp32 [E][R][C] -> dst bf16.
//   mode 0: dst [E][C][R]            (plain B^T, used for w2)
//   mode 1: dst [E][2C][R], col f -> row (f>>5)*64 +      (f&31)   (w1 slots)
//   mode 2: dst [E][2C][R], col f -> row (f>>5)*64 + 32 + (f&31)   (w3 slots)
// Modes 1/2 build the 32-col-interleaved dual weight for the fused SwiGLU GEMM.
// ---------------------------------------------------------------------------
__global__ __launch_bounds__(256) void trans_kernel(const float* __restrict__ src,
                                                    bf16* __restrict__ dst,
                                                    int R, int C, int mode) {
    __shared__ unsigned short lt[64 * 72];   // stride 72 shorts = 144B (16B-aligned rows)
    const int e  = blockIdx.z;
    const int c0 = blockIdx.x * 64;
    const int r0 = blockIdx.y * 64;
    const float* s = src + (size_t)e * R * C;
    unsigned short* dp = (unsigned short*)dst + (size_t)e * R * C * (mode ? 2 : 1);
    const int t  = threadIdx.x;
    const int tr = t >> 4;
    const int tc = (t & 15) * 4;
    #pragma unroll
    for (int rr = 0; rr < 4; ++rr) {
        const int r = tr + rr * 16;
        const float4 v = *(const float4*)(s + (size_t)(r0 + r) * C + c0 + tc);
        lt[(tc + 0) * 72 + r] = f2b(v.x);
        lt[(tc + 1) * 72 + r] = f2b(v.y);
        lt[(tc + 2) * 72 + r] = f2b(v.z);
        lt[(tc + 3) * 72 + r] = f2b(v.w);
    }
    __syncthreads();
    const int oc  = t >> 2;
    const int seg = (t & 3) * 16;
    const uint4 a = *(const uint4*)&lt[oc * 72 + seg];
    const uint4 b = *(const uint4*)&lt[oc * 72 + seg + 8];
    const int f  = c0 + oc;
    const int fr = mode ? ((f >> 5) * 64 + ((mode == 2) ? 32 : 0) + (f & 31)) : f;
    unsigned short* orow = dp + (size_t)fr * R + (r0 + seg);
    *(uint4*)(orow)     = a;
    *(uint4*)(orow + 8) = b;
}

// ---------------------------------------------------------------------------
// Gate: fp32 logits (wave per token), top-2, softmax, per-expert counts
// ---------------------------------------------------------------------------
__global__ __launch_bounds__(256) void gate_kernel(const float* __restrict__ x,
                                                   const float* __restrict__ gw,
                                                   int* __restrict__ tki,
                                                   float* __restrict__ tkw,
                                                   int* __restrict__ counts) {
    const int t    = blockIdx.x * 4 + (threadIdx.x >> 6);
    const int lane = threadIdx.x & 63;
    const float* xr = x + (size_t)t * D_DIM;
    float acc[E_NUM];
    #pragma unroll
    for (int e = 0; e < E_NUM; ++e) acc[e] = 0.f;
    for (int j = 0; j < 16; ++j) {
        const int d = lane + 64 * j;
        const float xv = xr[d];
        const float* g = gw + (size_t)d * E_NUM;
        #pragma unroll
        for (int e = 0; e < E_NUM; ++e) acc[e] += xv * g[e];
    }
    #pragma unroll
    for (int off = 32; off >= 1; off >>= 1) {
        #pragma unroll
        for (int e = 0; e < E_NUM; ++e) acc[e] += __shfl_xor(acc[e], off);
    }
    if (lane == 0) {
        int b0 = 0; float v0 = acc[0];
        #pragma unroll
        for (int e = 1; e < E_NUM; ++e) if (acc[e] > v0) { v0 = acc[e]; b0 = e; }
        int b1 = -1; float v1 = -1e30f;
        #pragma unroll
        for (int e = 0; e < E_NUM; ++e) if (e != b0 && acc[e] > v1) { v1 = acc[e]; b1 = e; }
        const float ex = expf(v1 - v0);           // v1 <= v0
        const float w0 = 1.f / (1.f + ex);
        const float w1 = ex * w0;
        tki[t * 2]     = b0;  tkw[t * 2]     = w0;
        tki[t * 2 + 1] = b1;  tkw[t * 2 + 1] = w1;
        atomicAdd(&counts[b0], 1);
        atomicAdd(&counts[b1], 1);
    }
}

// ---------------------------------------------------------------------------
// Scan: 128-aligned exclusive offsets per expert
// ---------------------------------------------------------------------------
__global__ void scan_kernel(const int* __restrict__ counts, int* __restrict__ aoff,
                            int* __restrict__ cursor) {
    if (threadIdx.x == 0) {
        int off = 0;
        #pragma unroll
        for (int e = 0; e < E_NUM; ++e) {
            aoff[e]   = off;
            cursor[e] = off;
            off += (counts[e] + 127) & ~127;
        }
        aoff[E_NUM] = off;
    }
}

// ---------------------------------------------------------------------------
// Gather: assign permuted rows, record slot->row, convert x rows to bf16
// ---------------------------------------------------------------------------
__global__ __launch_bounds__(256) void gather_kernel(const float* __restrict__ x,
                                                     const int* __restrict__ tki,
                                                     int* __restrict__ cursor,
                                                     int* __restrict__ s2r,
                                                     bf16* __restrict__ xp) {
    const int slot = blockIdx.x * 4 + (threadIdx.x >> 6);
    const int lane = threadIdx.x & 63;
    const int t = slot >> 1;
    int row = 0;
    if (lane == 0) {
        const int e = tki[slot];
        row = atomicAdd(&cursor[e], 1);
        s2r[slot] = row;
    }
    row = __shfl(row, 0);
    const float* xr = x + (size_t)t * D_DIM + lane * 16;
    unsigned short* dst = (unsigned short*)xp + (size_t)row * D_DIM + lane * 16;
    uint32_t u[8];
    #pragma unroll
    for (int q = 0; q < 4; ++q) {
        const float4 v = *(const float4*)(xr + q * 4);
        u[q * 2]     = (uint32_t)f2b(v.x) | ((uint32_t)f2b(v.y) << 16);
        u[q * 2 + 1] = (uint32_t)f2b(v.z) | ((uint32_t)f2b(v.w) << 16);
    }
    ((uint4*)dst)[0] = make_uint4(u[0], u[1], u[2], u[3]);
    ((uint4*)dst)[1] = make_uint4(u[4], u[5], u[6], u[7]);
}

// ---------------------------------------------------------------------------
// GEMM1: fused SwiGLU, 256x256x64 phase-pipelined (T2+T3+T4+T5 template).
//   A  = xp  [RCAP][1024] bf16 (rows per-expert, 128-aligned regions)
//   B  = wb13t [E][8192][1024] bf16: 64-row groups = [w1 cols g*32..+31 | w3 same]
//   8 waves (2M x 4N), per-wave 128x64 output, acc[8][4] f32x4.
//   LDS: A 2dbuf x 2half x 128rows x 128B = 64KB, B same = 128KB total.
//   XOR swizzle: phys 16B-slot = logical ^ (row&7); applied to global source col
//   (gload_lds dest is linear) AND to the ds_read address (rule 21).
//   Per K-tile: 4 phases, each {ds_read subtile || stage 1 half-tile -> barrier
//   -> lgkmcnt(0) -> setprio(1)+16 MFMA+setprio(0) -> barrier}; counted
//   vmcnt(4) once per tile, never 0 in the loop (T4).
//   Release order makes staging race-free: B-halves of buf c are fully read by
//   end of phase 1, A-halves by end of phase 2; we stage A(u+1) at phases 0/1
//   (other buffer) and B(u+2) at phases 2/3 (this buffer, after release).
// ---------------------------------------------------------------------------
__global__ __launch_bounds__(512, 2) void gemm1_kernel(const bf16* __restrict__ xp,
                                                       const bf16* __restrict__ wb13t,
                                                       bf16* __restrict__ hb,
                                                       const int* __restrict__ aoff,
                                                       const int* __restrict__ counts) {
    __shared__ __align__(16) char As[65536];
    __shared__ __align__(16) char Bs[65536];

    // block -> (expert, local 256-row m-block); grid.y = 72 >= sum(ceil(cnt/256))
    const int nt = blockIdx.x;
    int bm = blockIdx.y;
    int e  = 0;
    for (; e < E_NUM; ++e) {
        const int nbi = (counts[e] + 255) >> 8;
        if (bm < nbi) break;
        bm -= nbi;
    }
    if (e >= E_NUM) return;
    const int m_base = aoff[e] + bm * 256;
    const int row_hi = aoff[e + 1];          // store mask: don't stomp next expert

    const int tid  = threadIdx.x;
    const int w    = tid >> 6;               // 0..7
    const int lane = tid & 63;
    const int wm   = w >> 2;                 // 0..1 (M half)
    const int wn   = w & 3;                  // 0..3 (N quarter)

    // ---- staging constants (linear LDS dest; swizzle folded into global col)
    const int    lsub = lane >> 3;                                // 0..7
    const size_t swz  = (size_t)(((lane & 7) ^ lsub) << 3);       // elems
    const bf16* Ag = xp    + (size_t)m_base * D_DIM;
    const bf16* Bg = wb13t + ((size_t)e * (2 * F_DIM) + (size_t)nt * 256) * D_DIM;
    char* sAd = As + w * 2048 + lane * 16;   // + c*32768 + h*16384 + j*1024
    char* sBd = Bs + w * 2048 + lane * 16;
    const int rst = w * 16 + lsub;           // staging row base (j adds 8, h adds 128)

#define G1_STAGE_A(cc, kt, h)                                                         \
    do {                                                                              \
        const size_t kcol = (size_t)(kt) * 64 + swz;                                  \
        gload_lds16(Ag + (size_t)((h) * 128 + rst) * D_DIM + kcol,                    \
                    sAd + (cc) * 32768 + (h) * 16384);                                \
        gload_lds16(Ag + (size_t)((h) * 128 + rst + 8) * D_DIM + kcol,                \
                    sAd + (cc) * 32768 + (h) * 16384 + 1024);                         \
    } while (0)
#define G1_STAGE_B(cc, kt, h)                                                         \
    do {                                                                              \
        const size_t kcol = (size_t)(kt) * 64 + swz;                                  \
        gload_lds16(Bg + (size_t)((h) * 128 + rst) * D_DIM + kcol,                    \
                    sBd + (cc) * 32768 + (h) * 16384);                                \
        gload_lds16(Bg + (size_t)((h) * 128 + rst + 8) * D_DIM + kcol,                \
                    sBd + (cc) * 32768 + (h) * 16384 + 1024);                         \
    } while (0)

    // ---- fragment read constants (swizzled): row&7 == fm&7 for all frags
    const int fm  = lane & 15;
    const int kq  = lane >> 4;                                  // 0..3
    const int kg0 = ((kq       ^ (fm & 7)) << 4);               // ks=0 byte slot
    const int kg1 = (((4 | kq) ^ (fm & 7)) << 4);               // ks=1 byte slot
    const char* Arb = As + wm * 16384 + fm * 128;
    const char* Brb = Bs + (wn >> 1) * 16384 + ((wn & 1) * 64 + fm) * 128;

    f32x4 acc[8][4] = {};
    bf16x8 aF[4][2], b0F[2][2], b1F[2][2];

    // ---- prologue: A(0),B(0) -> buf0 ; B(1) -> buf1 ; wait tile0 only
    G1_STAGE_A(0, 0, 0); G1_STAGE_A(0, 0, 1);
    G1_STAGE_B(0, 0, 0); G1_STAGE_B(0, 0, 1);
    G1_STAGE_B(1, 1, 0); G1_STAGE_B(1, 1, 1);
    asm volatile("s_waitcnt vmcnt(4)" ::: "memory");
    __builtin_amdgcn_s_barrier();
    __builtin_amdgcn_sched_barrier(0);

    for (int u = 0; u < D_DIM / 64; ++u) {
        const int c = u & 1;
        const char* Ar = Arb + c * 32768;
        const char* Br = Brb + c * 32768;

        // ======== phase 0: read A(mh0)+B(nh0); stage A-h0(u+1); MFMA q(0,0)
        #pragma unroll
        for (int i = 0; i < 4; ++i) {
            aF[i][0] = *(const bf16x8*)(Ar + i * 2048 + kg0);
            aF[i][1] = *(const bf16x8*)(Ar + i * 2048 + kg1);
        }
        #pragma unroll
        for (int j = 0; j < 2; ++j) {
            b0F[j][0] = *(const bf16x8*)(Br + j * 2048 + kg0);
            b0F[j][1] = *(const bf16x8*)(Br + j * 2048 + kg1);
        }
        if (u + 1 < D_DIM / 64) G1_STAGE_A(c ^ 1, u + 1, 0);
        __builtin_amdgcn_s_barrier();
        asm volatile("s_waitcnt lgkmcnt(0)" ::: "memory");
        __builtin_amdgcn_s_setprio(1);
        #pragma unroll
        for (int i = 0; i < 4; ++i)
            #pragma unroll
            for (int j = 0; j < 2; ++j) {
                acc[i][j] = __builtin_amdgcn_mfma_f32_16x16x32_bf16(aF[i][0], b0F[j][0], acc[i][j], 0, 0, 0);
                acc[i][j] = __builtin_amdgcn_mfma_f32_16x16x32_bf16(aF[i][1], b0F[j][1], acc[i][j], 0, 0, 0);
            }
        __builtin_amdgcn_s_setprio(0);
        __builtin_amdgcn_s_barrier();

        // ======== phase 1: read B(nh1); stage A-h1(u+1); MFMA q(0,1)
        #pragma unroll
        for (int j = 0; j < 2; ++j) {
            b1F[j][0] = *(const bf16x8*)(Br + (j + 2) * 2048 + kg0);
            b1F[j][1] = *(const bf16x8*)(Br + (j + 2) * 2048 + kg1);
        }
        if (u + 1 < D_DIM / 64) G1_STAGE_A(c ^ 1, u + 1, 1);
        __builtin_amdgcn_s_barrier();
        asm volatile("s_waitcnt lgkmcnt(0)" ::: "memory");
        __builtin_amdgcn_s_setprio(1);
        #pragma unroll
        for (int i = 0; i < 4; ++i)
            #pragma unroll
            for (int j = 0; j < 2; ++j) {
                acc[i][j + 2] = __builtin_amdgcn_mfma_f32_16x16x32_bf16(aF[i][0], b1F[j][0], acc[i][j + 2], 0, 0, 0);
                acc[i][j + 2] = __builtin_amdgcn_mfma_f32_16x16x32_bf16(aF[i][1], b1F[j][1], acc[i][j + 2], 0, 0, 0);
            }
        __builtin_amdgcn_s_setprio(0);
        __builtin_amdgcn_s_barrier();

        // ======== phase 2: read A(mh1); stage B-h0(u+2) (released after p1); MFMA q(1,0)
        #pragma unroll
        for (int i = 0; i < 4; ++i) {
            aF[i][0] = *(const bf16x8*)(Ar + (i + 4) * 2048 + kg0);
            aF[i][1] = *(const bf16x8*)(Ar + (i + 4) * 2048 + kg1);
        }
        if (u + 2 < D_DIM / 64) G1_STAGE_B(c, u + 2, 0);
        __builtin_amdgcn_s_barrier();
        asm volatile("s_waitcnt lgkmcnt(0)" ::: "memory");
        __builtin_amdgcn_s_setprio(1);
        #pragma unroll
        for (int i = 0; i < 4; ++i)
            #pragma unroll
            for (int j = 0; j < 2; ++j) {
                acc[i + 4][j] = __builtin_amdgcn_mfma_f32_16x16x32_bf16(aF[i][0], b0F[j][0], acc[i + 4][j], 0, 0, 0);
                acc[i + 4][j] = __builtin_amdgcn_mfma_f32_16x16x32_bf16(aF[i][1], b0F[j][1], acc[i + 4][j], 0, 0, 0);
            }
        __builtin_amdgcn_s_setprio(0);
        __builtin_amdgcn_s_barrier();

        // ======== phase 3: stage B-h1(u+2); MFMA q(1,1) (operands already in regs)
        if (u + 2 < D_DIM / 64) G1_STAGE_B(c, u + 2, 1);
        __builtin_amdgcn_s_setprio(1);
        #pragma unroll
        for (int i = 0; i < 4; ++i)
            #pragma unroll
            for (int j = 0; j < 2; ++j) {
                acc[i + 4][j + 2] = __builtin_amdgcn_mfma_f32_16x16x32_bf16(aF[i][0], b1F[j][0], acc[i + 4][j + 2], 0, 0, 0);
                acc[i + 4][j + 2] = __builtin_amdgcn_mfma_f32_16x16x32_bf16(aF[i][1], b1F[j][1], acc[i + 4][j + 2], 0, 0, 0);
            }
        __builtin_amdgcn_s_setprio(0);

        // ======== tile boundary: counted wait (A(u+1)&B(u+1) done; B(u+2) in flight)
        if (u == D_DIM / 64 - 1) break;
        if (u + 2 < D_DIM / 64) {
            asm volatile("s_waitcnt vmcnt(4)" ::: "memory");
        } else {
            asm volatile("s_waitcnt vmcnt(0)" ::: "memory");
        }
        __builtin_amdgcn_s_barrier();
        __builtin_amdgcn_sched_barrier(0);
    }

    // ---- epilogue: silu(s1)*s3 -> bf16  (C/D: col=lane&15, row=(lane>>4)*4+reg)
    unsigned short* hw = (unsigned short*)hb;
    const int g    = nt * 4 + wn;                 // 32-col h group
    const int colb = g * 32 + fm;
    const int rb0  = m_base + wm * 128 + (kq << 2);
    #pragma unroll
    for (int i = 0; i < 8; ++i) {
        #pragma unroll
        for (int r = 0; r < 4; ++r) {
            const int row = rb0 + i * 16 + r;
            if (row < row_hi) {
                #pragma unroll
                for (int jj = 0; jj < 2; ++jj) {
                    const float s1 = acc[i][jj][r];
                    const float s3 = acc[i][jj + 2][r];
                    const float hv = (s1 / (1.0f + __expf(-s1))) * s3;
                    hw[(size_t)row * F_DIM + colb + jj * 16] = f2b(hv);
                }
            }
        }
    }
#undef G1_STAGE_A
#undef G1_STAGE_B
}

// ---------------------------------------------------------------------------
// GEMM2: y = H @ W2 (per permuted row, fp32 out, no atomics)  [unchanged]
//   hb [RCAP][F] bf16, wb2t [E][D][F] bf16 (B^T), yb [RCAP][D] fp32
// ---------------------------------------------------------------------------
__global__ __launch_bounds__(256, 2) void gemm2_kernel(const bf16* __restrict__ hb,
                                                       const bf16* __restrict__ wb2t,
                                                       float* __restrict__ yb,
                                                       const int* __restrict__ aoff,
                                                       const int* __restrict__ counts) {
    __shared__ bf16 As[128 * 32];
    __shared__ bf16 Bs[128 * 32];

    const int m_base = blockIdx.y * 128;
    int e = 0;
    #pragma unroll
    for (int i = 1; i < E_NUM; ++i) if (m_base >= aoff[i]) e = i;
    if (m_base - aoff[e] >= counts[e]) return;

    const int nt   = blockIdx.x;
    const int tid  = threadIdx.x;
    const int w    = tid >> 6;
    const int lane = tid & 63;
    const int wm   = w & 1, wn = w >> 1;

    const bf16* Ab = hb + (size_t)m_base * F_DIM;
    const bf16* Bb = wb2t + ((size_t)e * D_DIM + (size_t)nt * 128) * F_DIM;

    const int lr16 = lane >> 2;
    const int cg   = lane & 3;
    const int srow = w * 32 + lr16;
    const int scol = (cg ^ ((lr16 >> 1) & 3)) * 8;
    const int ldsbase = w * 1024;
    const int fm = lane & 15;
    const int fk = (((lane >> 4) ^ ((fm >> 1) & 3))) * 8;

    f32x4 acc[4][4] = {};

    for (int kt = 0; kt < F_DIM / 32; ++kt) {
        const int k0 = kt * 32;
        #pragma unroll
        for (int j = 0; j < 2; ++j) {
            const size_t go = (size_t)(srow + j * 16) * F_DIM + (k0 + scol);
            gload_lds16(Ab + go, &As[ldsbase + j * 512]);
            gload_lds16(Bb + go, &Bs[ldsbase + j * 512]);
        }
        __syncthreads();
        bf16x8 af[4], bfr[4];
        #pragma unroll
        for (int i = 0; i < 4; ++i) {
            af[i]  = *(const bf16x8*)&As[(wm * 64 + i * 16 + fm) * 32 + fk];
            bfr[i] = *(const bf16x8*)&Bs[(wn * 64 + i * 16 + fm) * 32 + fk];
        }
        #pragma unroll
        for (int i = 0; i < 4; ++i) {
            #pragma unroll
            for (int jn = 0; jn < 4; ++jn) {
                acc[i][jn] = __builtin_amdgcn_mfma_f32_16x16x32_bf16(af[i], bfr[jn], acc[i][jn], 0, 0, 0);
            }
        }
        __syncthreads();
    }

    #pragma unroll
    for (int i = 0; i < 4; ++i) {
        const int rb = m_base + wm * 64 + i * 16 + (lane >> 4) * 4;
        #pragma unroll
        for (int r = 0; r < 4; ++r) {
            float* yrow = yb + (size_t)(rb + r) * D_DIM;
            #pragma unroll
            for (int jn = 0; jn < 4; ++jn) {
                const int col = nt * 128 + wn * 64 + jn * 16 + (lane & 15);
                yrow[col] = acc[i][jn][r];
            }
        }
    }
}

// ---------------------------------------------------------------------------
// Combine: out[t] = w0*y[row0] + w1*y[row1]   (fully overwrites d_out)
// ---------------------------------------------------------------------------
__global__ __launch_bounds__(256) void combine_kernel(const float* __restrict__ yb,
                                                      const int* __restrict__ s2r,
                                                      const float* __restrict__ tkw,
                                                      float* __restrict__ out) {
    const int idx = blockIdx.x * 256 + threadIdx.x;   // one float4 per thread
    const int t = idx >> 8;                           // 256 float4 per token
    const int c = (idx & 255) * 4;
    const int r0 = s2r[t * 2], r1 = s2r[t * 2 + 1];
    const float w0 = tkw[t * 2], w1 = tkw[t * 2 + 1];
    const float4 a = *(const float4*)(yb + (size_t)r0 * D_DIM + c);
    const float4 b = *(const float4*)(yb + (size_t)r1 * D_DIM + c);
    float4 o;
    o.x = w0 * a.x + w1 * b.x;
    o.y = w0 * a.y + w1 * b.y;
    o.z = w0 * a.z + w1 * b.z;
    o.w = w0 * a.w + w1 * b.w;
    *(float4*)(out + (size_t)t * D_DIM + c) = o;
}

// ---------------------------------------------------------------------------
extern "C" void kernel_launch(void* const* d_in, const int* in_sizes, int n_in,
                              void* d_out, int out_size, void* d_ws, size_t ws_size,
                              hipStream_t stream) {
    const float* x  = (const float*)d_in[0];
    const float* gw = (const float*)d_in[1];
    const float* w1 = (const float*)d_in[2];
    const float* w3 = (const float*)d_in[3];
    const float* w2 = (const float*)d_in[4];
    float* out = (float*)d_out;

    char* ws = (char*)d_ws;
    // [0, 134.2MB)            wb13t [E][2F][D] bf16 (w1/w3 interleaved, dead after gemm1)
    //   alias [0, 67.1MB)     wb2t  [E][D][F]  bf16 (built after gemm1)
    //   alias [67.1, 138.4MB) yb    [RCAP][D]  fp32 (written by gemm2; overlaps dead
    //                                               wb13t tail + dead xp head)
    // [134.2, 169.9MB)        xp    [RCAP][D]  bf16 (dead after gemm1)
    // [169.9, 312.5MB)        hb    [RCAP][F]  bf16
    bf16*  wb13t = (bf16*)(ws);
    bf16*  wb2t  = (bf16*)(ws);
    float* yb    = (float*)(ws + (size_t)67108864);
    bf16*  xp    = (bf16*)(ws + (size_t)134217728);
    size_t off   = (size_t)134217728 + (size_t)RCAP * D_DIM * 2;
    bf16*  hb    = (bf16*)(ws + off); off += (size_t)RCAP * F_DIM * 2;
    int*   tki = (int*)(ws + off);   off += (size_t)T_TOK * 2 * 4;
    float* tkw = (float*)(ws + off); off += (size_t)T_TOK * 2 * 4;
    int* counts = (int*)(ws + off);  off += 64;
    int* cursor = (int*)(ws + off);  off += 64;
    int* aoff   = (int*)(ws + off);  off += 64;
    int* s2r    = (int*)(ws + off);  off += (size_t)T_TOK * 2 * 4;

    hipMemsetAsync(counts, 0, 64, stream);

    gate_kernel<<<T_TOK / 4, 256, 0, stream>>>(x, gw, tki, tkw, counts);
    scan_kernel<<<1, 64, 0, stream>>>(counts, aoff, cursor);
    gather_kernel<<<(T_TOK * 2) / 4, 256, 0, stream>>>(x, tki, cursor, s2r, xp);

    trans_kernel<<<dim3(F_DIM / 64, D_DIM / 64, E_NUM), 256, 0, stream>>>(w1, wb13t, D_DIM, F_DIM, 1);
    trans_kernel<<<dim3(F_DIM / 64, D_DIM / 64, E_NUM), 256, 0, stream>>>(w3, wb13t, D_DIM, F_DIM, 2);

    // grid.y = 72 >= sum_e ceil(counts[e]/256) (16384/256 + 8)
    gemm1_kernel<<<dim3(2 * F_DIM / 256, 72), 512, 0, stream>>>(xp, wb13t, hb, aoff, counts);

    trans_kernel<<<dim3(D_DIM / 64, F_DIM / 64, E_NUM), 256, 0, stream>>>(w2, wb2t, F_DIM, D_DIM, 0);

    gemm2_kernel<<<dim3(D_DIM / 128, MT), 256, 0, stream>>>(hb, wb2t, yb, aoff, counts);

    combine_kernel<<<(T_TOK * 256) / 256, 256, 0, stream>>>(yb, s2r, tkw, out);
}

// Round 2
// 1391.758 us; speedup vs baseline: 1.0147x; 1.0147x over previous
//
#include <hip/hip_runtime.h>
#include <stdint.h>

#define T_TOK 8192
#define D_DIM 1024
#define F_DIM 4096
#define E_NUM 8
#define RCAP  17408   // 136 * 128 >= 16384 + 8*127 (per-expert 128-aligned regions)
#define MT    136

typedef __bf16 bf16;
typedef __bf16 bf16x8 __attribute__((ext_vector_type(8)));
typedef float  f32x4  __attribute__((ext_vector_type(4)));

typedef const __attribute__((address_space(1))) void* gptr1;
typedef __attribute__((address_space(3))) void* lptr3;

__device__ __forceinline__ void gload_lds16(const void* g, void* l) {
    // async global->LDS DMA, 16B/lane; LDS dest = wave-uniform base + lane*16
    __builtin_amdgcn_global_load_lds((gptr1)g, (lptr3)l, 16, 0, 0);
}

__device__ __forceinline__ unsigned short f2b(float f) {
    // fp32 -> bf16 round-to-nearest-even
    uint32_t u = __float_as_uint(f);
    u = (u + 0x7FFFu + ((u >> 16) & 1u)) >> 16;
    return (unsigned short)u;
}

// ---------------------------------------------------------------------------
// Transpose-convert: src fp32 [E][R][C] -> dst bf16.
//   mode 0: dst [E][C][R]            (plain B^T, used for w2)
//   mode 1: dst [E][2C][R], col f -> row (f>>5)*64 +      (f&31)   (w1 slots)
//   mode 2: dst [E][2C][R], col f -> row (f>>5)*64 + 32 + (f&31)   (w3 slots)
// LDS scheme: stage fp32 tile UN-transposed [64][68] (stride 272B, 16B-aligned,
// b128 writes conflict-free); transpose on the read side (b32 scalar reads,
// <=4-way). Replaces the old short[64][72] scheme whose 2-byte column writes
// had 8-way bank aliasing.
// ---------------------------------------------------------------------------
__global__ __launch_bounds__(256) void trans_kernel(const float* __restrict__ src,
                                                    bf16* __restrict__ dst,
                                                    int R, int C, int mode) {
    __shared__ float lt[64 * 68];
    const int e  = blockIdx.z;
    const int c0 = blockIdx.x * 64;
    const int r0 = blockIdx.y * 64;
    const float* s = src + (size_t)e * R * C;
    unsigned short* dp = (unsigned short*)dst + (size_t)e * R * C * (mode ? 2 : 1);
    const int t  = threadIdx.x;
    const int tr = t >> 4;
    const int tc = (t & 15) * 4;
    #pragma unroll
    for (int rr = 0; rr < 4; ++rr) {
        const int r = tr + rr * 16;
        const float4 v = *(const float4*)(s + (size_t)(r0 + r) * C + c0 + tc);
        *(float4*)&lt[r * 68 + tc] = v;
    }
    __syncthreads();
    const int oc  = t >> 2;           // 0..63: logical output column f
    const int seg = (t & 3) * 16;     // 16-element segment along R
    __attribute__((aligned(16))) unsigned short ob[16];
    #pragma unroll
    for (int i = 0; i < 16; ++i) ob[i] = f2b(lt[(seg + i) * 68 + oc]);
    const int f  = c0 + oc;
    const int fr = mode ? ((f >> 5) * 64 + ((mode == 2) ? 32 : 0) + (f & 31)) : f;
    unsigned short* orow = dp + (size_t)fr * R + (r0 + seg);
    *(uint4*)(orow)     = *(const uint4*)&ob[0];
    *(uint4*)(orow + 8) = *(const uint4*)&ob[8];
}

// ---------------------------------------------------------------------------
// Gate: fp32 logits (wave per token), top-2, softmax, per-expert counts
// ---------------------------------------------------------------------------
__global__ __launch_bounds__(256) void gate_kernel(const float* __restrict__ x,
                                                   const float* __restrict__ gw,
                                                   int* __restrict__ tki,
                                                   float* __restrict__ tkw,
                                                   int* __restrict__ counts) {
    const int t    = blockIdx.x * 4 + (threadIdx.x >> 6);
    const int lane = threadIdx.x & 63;
    const float* xr = x + (size_t)t * D_DIM;
    float acc[E_NUM];
    #pragma unroll
    for (int e = 0; e < E_NUM; ++e) acc[e] = 0.f;
    for (int j = 0; j < 16; ++j) {
        const int d = lane + 64 * j;
        const float xv = xr[d];
        const float* g = gw + (size_t)d * E_NUM;
        #pragma unroll
        for (int e = 0; e < E_NUM; ++e) acc[e] += xv * g[e];
    }
    #pragma unroll
    for (int off = 32; off >= 1; off >>= 1) {
        #pragma unroll
        for (int e = 0; e < E_NUM; ++e) acc[e] += __shfl_xor(acc[e], off);
    }
    if (lane == 0) {
        int b0 = 0; float v0 = acc[0];
        #pragma unroll
        for (int e = 1; e < E_NUM; ++e) if (acc[e] > v0) { v0 = acc[e]; b0 = e; }
        int b1 = -1; float v1 = -1e30f;
        #pragma unroll
        for (int e = 0; e < E_NUM; ++e) if (e != b0 && acc[e] > v1) { v1 = acc[e]; b1 = e; }
        const float ex = expf(v1 - v0);           // v1 <= v0
        const float w0 = 1.f / (1.f + ex);
        const float w1 = ex * w0;
        tki[t * 2]     = b0;  tkw[t * 2]     = w0;
        tki[t * 2 + 1] = b1;  tkw[t * 2 + 1] = w1;
        atomicAdd(&counts[b0], 1);
        atomicAdd(&counts[b1], 1);
    }
}

// ---------------------------------------------------------------------------
// Scan: 128-aligned exclusive offsets per expert
// ---------------------------------------------------------------------------
__global__ void scan_kernel(const int* __restrict__ counts, int* __restrict__ aoff,
                            int* __restrict__ cursor) {
    if (threadIdx.x == 0) {
        int off = 0;
        #pragma unroll
        for (int e = 0; e < E_NUM; ++e) {
            aoff[e]   = off;
            cursor[e] = off;
            off += (counts[e] + 127) & ~127;
        }
        aoff[E_NUM] = off;
    }
}

// ---------------------------------------------------------------------------
// Gather: assign permuted rows, record slot->row, convert x rows to bf16
// ---------------------------------------------------------------------------
__global__ __launch_bounds__(256) void gather_kernel(const float* __restrict__ x,
                                                     const int* __restrict__ tki,
                                                     int* __restrict__ cursor,
                                                     int* __restrict__ s2r,
                                                     bf16* __restrict__ xp) {
    const int slot = blockIdx.x * 4 + (threadIdx.x >> 6);
    const int lane = threadIdx.x & 63;
    const int t = slot >> 1;
    int row = 0;
    if (lane == 0) {
        const int e = tki[slot];
        row = atomicAdd(&cursor[e], 1);
        s2r[slot] = row;
    }
    row = __shfl(row, 0);
    const float* xr = x + (size_t)t * D_DIM + lane * 16;
    unsigned short* dst = (unsigned short*)xp + (size_t)row * D_DIM + lane * 16;
    uint32_t u[8];
    #pragma unroll
    for (int q = 0; q < 4; ++q) {
        const float4 v = *(const float4*)(xr + q * 4);
        u[q * 2]     = (uint32_t)f2b(v.x) | ((uint32_t)f2b(v.y) << 16);
        u[q * 2 + 1] = (uint32_t)f2b(v.z) | ((uint32_t)f2b(v.w) << 16);
    }
    ((uint4*)dst)[0] = make_uint4(u[0], u[1], u[2], u[3]);
    ((uint4*)dst)[1] = make_uint4(u[4], u[5], u[6], u[7]);
}

// ---------------------------------------------------------------------------
// GEMM1: fused SwiGLU, 256x256x64 phase-pipelined (T2+T3+T4+T5 template).
//   NEW (R2): bijective XCD-chunk swizzle — hw-linear block id -> logical
//   (bm, nt) such that each XCD owns a contiguous bm-chunk x all nt:
//   both A-panel sharers (same bm) and B-tile sharers (same nt, bm in chunk)
//   become XCD-L2-local.  Previously A-panels were pulled from LLC 8x.
// ---------------------------------------------------------------------------
__global__ __launch_bounds__(512, 2) void gemm1_kernel(const bf16* __restrict__ xp,
                                                       const bf16* __restrict__ wb13t,
                                                       bf16* __restrict__ hb,
                                                       const int* __restrict__ aoff,
                                                       const int* __restrict__ counts) {
    __shared__ __align__(16) char As[65536];
    __shared__ __align__(16) char Bs[65536];

    // XCD-chunk swizzle: grid = (32, 72) -> flat in [0,2304), 2304/8 = 288.
    const int flat    = blockIdx.y * 32 + blockIdx.x;
    const int logical = (flat & 7) * 288 + (flat >> 3);
    const int nt      = logical & 31;
    int bm            = logical >> 5;

    int e = 0;
    for (; e < E_NUM; ++e) {
        const int nbi = (counts[e] + 255) >> 8;
        if (bm < nbi) break;
        bm -= nbi;
    }
    if (e >= E_NUM) return;
    const int m_base = aoff[e] + bm * 256;
    const int row_hi = aoff[e + 1];          // store mask: don't stomp next expert

    const int tid  = threadIdx.x;
    const int w    = tid >> 6;               // 0..7
    const int lane = tid & 63;
    const int wm   = w >> 2;                 // 0..1 (M half)
    const int wn   = w & 3;                  // 0..3 (N quarter)

    // ---- staging constants (linear LDS dest; swizzle folded into global col)
    const int    lsub = lane >> 3;                                // 0..7
    const size_t swz  = (size_t)(((lane & 7) ^ lsub) << 3);       // elems
    const bf16* Ag = xp    + (size_t)m_base * D_DIM;
    const bf16* Bg = wb13t + ((size_t)e * (2 * F_DIM) + (size_t)nt * 256) * D_DIM;
    char* sAd = As + w * 2048 + lane * 16;   // + c*32768 + h*16384 + j*1024
    char* sBd = Bs + w * 2048 + lane * 16;
    const int rst = w * 16 + lsub;           // staging row base (j adds 8, h adds 128)

#define G1_STAGE_A(cc, kt, h)                                                         \
    do {                                                                              \
        const size_t kcol = (size_t)(kt) * 64 + swz;                                  \
        gload_lds16(Ag + (size_t)((h) * 128 + rst) * D_DIM + kcol,                    \
                    sAd + (cc) * 32768 + (h) * 16384);                                \
        gload_lds16(Ag + (size_t)((h) * 128 + rst + 8) * D_DIM + kcol,                \
                    sAd + (cc) * 32768 + (h) * 16384 + 1024);                         \
    } while (0)
#define G1_STAGE_B(cc, kt, h)                                                         \
    do {                                                                              \
        const size_t kcol = (size_t)(kt) * 64 + swz;                                  \
        gload_lds16(Bg + (size_t)((h) * 128 + rst) * D_DIM + kcol,                    \
                    sBd + (cc) * 32768 + (h) * 16384);                                \
        gload_lds16(Bg + (size_t)((h) * 128 + rst + 8) * D_DIM + kcol,                \
                    sBd + (cc) * 32768 + (h) * 16384 + 1024);                         \
    } while (0)

    // ---- fragment read constants (swizzled): row&7 == fm&7 for all frags
    const int fm  = lane & 15;
    const int kq  = lane >> 4;                                  // 0..3
    const int kg0 = ((kq       ^ (fm & 7)) << 4);               // ks=0 byte slot
    const int kg1 = (((4 | kq) ^ (fm & 7)) << 4);               // ks=1 byte slot
    const char* Arb = As + wm * 16384 + fm * 128;
    const char* Brb = Bs + (wn >> 1) * 16384 + ((wn & 1) * 64 + fm) * 128;

    f32x4 acc[8][4] = {};
    bf16x8 aF[4][2], b0F[2][2], b1F[2][2];

    // ---- prologue: A(0),B(0) -> buf0 ; B(1) -> buf1 ; wait tile0 only
    G1_STAGE_A(0, 0, 0); G1_STAGE_A(0, 0, 1);
    G1_STAGE_B(0, 0, 0); G1_STAGE_B(0, 0, 1);
    G1_STAGE_B(1, 1, 0); G1_STAGE_B(1, 1, 1);
    asm volatile("s_waitcnt vmcnt(4)" ::: "memory");
    __builtin_amdgcn_s_barrier();
    __builtin_amdgcn_sched_barrier(0);

    for (int u = 0; u < D_DIM / 64; ++u) {
        const int c = u & 1;
        const char* Ar = Arb + c * 32768;
        const char* Br = Brb + c * 32768;

        // ======== phase 0: read A(mh0)+B(nh0); stage A-h0(u+1); MFMA q(0,0)
        #pragma unroll
        for (int i = 0; i < 4; ++i) {
            aF[i][0] = *(const bf16x8*)(Ar + i * 2048 + kg0);
            aF[i][1] = *(const bf16x8*)(Ar + i * 2048 + kg1);
        }
        #pragma unroll
        for (int j = 0; j < 2; ++j) {
            b0F[j][0] = *(const bf16x8*)(Br + j * 2048 + kg0);
            b0F[j][1] = *(const bf16x8*)(Br + j * 2048 + kg1);
        }
        if (u + 1 < D_DIM / 64) G1_STAGE_A(c ^ 1, u + 1, 0);
        __builtin_amdgcn_s_barrier();
        asm volatile("s_waitcnt lgkmcnt(0)" ::: "memory");
        __builtin_amdgcn_s_setprio(1);
        #pragma unroll
        for (int i = 0; i < 4; ++i)
            #pragma unroll
            for (int j = 0; j < 2; ++j) {
                acc[i][j] = __builtin_amdgcn_mfma_f32_16x16x32_bf16(aF[i][0], b0F[j][0], acc[i][j], 0, 0, 0);
                acc[i][j] = __builtin_amdgcn_mfma_f32_16x16x32_bf16(aF[i][1], b0F[j][1], acc[i][j], 0, 0, 0);
            }
        __builtin_amdgcn_s_setprio(0);
        __builtin_amdgcn_s_barrier();

        // ======== phase 1: read B(nh1); stage A-h1(u+1); MFMA q(0,1)
        #pragma unroll
        for (int j = 0; j < 2; ++j) {
            b1F[j][0] = *(const bf16x8*)(Br + (j + 2) * 2048 + kg0);
            b1F[j][1] = *(const bf16x8*)(Br + (j + 2) * 2048 + kg1);
        }
        if (u + 1 < D_DIM / 64) G1_STAGE_A(c ^ 1, u + 1, 1);
        __builtin_amdgcn_s_barrier();
        asm volatile("s_waitcnt lgkmcnt(0)" ::: "memory");
        __builtin_amdgcn_s_setprio(1);
        #pragma unroll
        for (int i = 0; i < 4; ++i)
            #pragma unroll
            for (int j = 0; j < 2; ++j) {
                acc[i][j + 2] = __builtin_amdgcn_mfma_f32_16x16x32_bf16(aF[i][0], b1F[j][0], acc[i][j + 2], 0, 0, 0);
                acc[i][j + 2] = __builtin_amdgcn_mfma_f32_16x16x32_bf16(aF[i][1], b1F[j][1], acc[i][j + 2], 0, 0, 0);
            }
        __builtin_amdgcn_s_setprio(0);
        __builtin_amdgcn_s_barrier();

        // ======== phase 2: read A(mh1); stage B-h0(u+2) (released after p1); MFMA q(1,0)
        #pragma unroll
        for (int i = 0; i < 4; ++i) {
            aF[i][0] = *(const bf16x8*)(Ar + (i + 4) * 2048 + kg0);
            aF[i][1] = *(const bf16x8*)(Ar + (i + 4) * 2048 + kg1);
        }
        if (u + 2 < D_DIM / 64) G1_STAGE_B(c, u + 2, 0);
        __builtin_amdgcn_s_barrier();
        asm volatile("s_waitcnt lgkmcnt(0)" ::: "memory");
        __builtin_amdgcn_s_setprio(1);
        #pragma unroll
        for (int i = 0; i < 4; ++i)
            #pragma unroll
            for (int j = 0; j < 2; ++j) {
                acc[i + 4][j] = __builtin_amdgcn_mfma_f32_16x16x32_bf16(aF[i][0], b0F[j][0], acc[i + 4][j], 0, 0, 0);
                acc[i + 4][j] = __builtin_amdgcn_mfma_f32_16x16x32_bf16(aF[i][1], b0F[j][1], acc[i + 4][j], 0, 0, 0);
            }
        __builtin_amdgcn_s_setprio(0);
        __builtin_amdgcn_s_barrier();

        // ======== phase 3: stage B-h1(u+2); MFMA q(1,1) (operands already in regs)
        if (u + 2 < D_DIM / 64) G1_STAGE_B(c, u + 2, 1);
        __builtin_amdgcn_s_setprio(1);
        #pragma unroll
        for (int i = 0; i < 4; ++i)
            #pragma unroll
            for (int j = 0; j < 2; ++j) {
                acc[i + 4][j + 2] = __builtin_amdgcn_mfma_f32_16x16x32_bf16(aF[i][0], b1F[j][0], acc[i + 4][j + 2], 0, 0, 0);
                acc[i + 4][j + 2] = __builtin_amdgcn_mfma_f32_16x16x32_bf16(aF[i][1], b1F[j][1], acc[i + 4][j + 2], 0, 0, 0);
            }
        __builtin_amdgcn_s_setprio(0);

        // ======== tile boundary: counted wait (A(u+1)&B(u+1) done; B(u+2) in flight)
        if (u == D_DIM / 64 - 1) break;
        if (u + 2 < D_DIM / 64) {
            asm volatile("s_waitcnt vmcnt(4)" ::: "memory");
        } else {
            asm volatile("s_waitcnt vmcnt(0)" ::: "memory");
        }
        __builtin_amdgcn_s_barrier();
        __builtin_amdgcn_sched_barrier(0);
    }

    // ---- epilogue: silu(s1)*s3 -> bf16  (C/D: col=lane&15, row=(lane>>4)*4+reg)
    unsigned short* hw = (unsigned short*)hb;
    const int g    = nt * 4 + wn;                 // 32-col h group
    const int colb = g * 32 + fm;
    const int rb0  = m_base + wm * 128 + (kq << 2);
    #pragma unroll
    for (int i = 0; i < 8; ++i) {
        #pragma unroll
        for (int r = 0; r < 4; ++r) {
            const int row = rb0 + i * 16 + r;
            if (row < row_hi) {
                #pragma unroll
                for (int jj = 0; jj < 2; ++jj) {
                    const float s1 = acc[i][jj][r];
                    const float s3 = acc[i][jj + 2][r];
                    const float hv = (s1 / (1.0f + __expf(-s1))) * s3;
                    hw[(size_t)row * F_DIM + colb + jj * 16] = f2b(hv);
                }
            }
        }
    }
#undef G1_STAGE_A
#undef G1_STAGE_B
}

// ---------------------------------------------------------------------------
// GEMM2: y = H @ W2 (per permuted row, fp32 out, no atomics)
//   NEW (R2): XCD-chunk swizzle.  Old mapping had XCD = nt for ALL blocks of
//   a given nt -> every XCD streamed the ENTIRE hb (138 MB) from LLC (8x
//   refetch, ~1.1 GB).  Swizzled: each XCD owns 17 consecutive bm x all 8 nt.
// ---------------------------------------------------------------------------
__global__ __launch_bounds__(256, 2) void gemm2_kernel(const bf16* __restrict__ hb,
                                                       const bf16* __restrict__ wb2t,
                                                       float* __restrict__ yb,
                                                       const int* __restrict__ aoff,
                                                       const int* __restrict__ counts) {
    __shared__ bf16 As[128 * 32];
    __shared__ bf16 Bs[128 * 32];

    // grid = (8, 136) -> flat in [0,1088), 1088/8 = 136.
    const int flat    = blockIdx.y * 8 + blockIdx.x;
    const int logical = (flat & 7) * 136 + (flat >> 3);
    const int nt      = logical & 7;
    const int m_base  = (logical >> 3) * 128;

    int e = 0;
    #pragma unroll
    for (int i = 1; i < E_NUM; ++i) if (m_base >= aoff[i]) e = i;
    if (m_base - aoff[e] >= counts[e]) return;

    const int tid  = threadIdx.x;
    const int w    = tid >> 6;
    const int lane = tid & 63;
    const int wm   = w & 1, wn = w >> 1;

    const bf16* Ab = hb + (size_t)m_base * F_DIM;
    const bf16* Bb = wb2t + ((size_t)e * D_DIM + (size_t)nt * 128) * F_DIM;

    const int lr16 = lane >> 2;
    const int cg   = lane & 3;
    const int srow = w * 32 + lr16;
    const int scol = (cg ^ ((lr16 >> 1) & 3)) * 8;
    const int ldsbase = w * 1024;
    const int fm = lane & 15;
    const int fk = (((lane >> 4) ^ ((fm >> 1) & 3))) * 8;

    f32x4 acc[4][4] = {};

    for (int kt = 0; kt < F_DIM / 32; ++kt) {
        const int k0 = kt * 32;
        #pragma unroll
        for (int j = 0; j < 2; ++j) {
            const size_t go = (size_t)(srow + j * 16) * F_DIM + (k0 + scol);
            gload_lds16(Ab + go, &As[ldsbase + j * 512]);
            gload_lds16(Bb + go, &Bs[ldsbase + j * 512]);
        }
        __syncthreads();
        bf16x8 af[4], bfr[4];
        #pragma unroll
        for (int i = 0; i < 4; ++i) {
            af[i]  = *(const bf16x8*)&As[(wm * 64 + i * 16 + fm) * 32 + fk];
            bfr[i] = *(const bf16x8*)&Bs[(wn * 64 + i * 16 + fm) * 32 + fk];
        }
        #pragma unroll
        for (int i = 0; i < 4; ++i) {
            #pragma unroll
            for (int jn = 0; jn < 4; ++jn) {
                acc[i][jn] = __builtin_amdgcn_mfma_f32_16x16x32_bf16(af[i], bfr[jn], acc[i][jn], 0, 0, 0);
            }
        }
        __syncthreads();
    }

    #pragma unroll
    for (int i = 0; i < 4; ++i) {
        const int rb = m_base + wm * 64 + i * 16 + (lane >> 4) * 4;
        #pragma unroll
        for (int r = 0; r < 4; ++r) {
            float* yrow = yb + (size_t)(rb + r) * D_DIM;
            #pragma unroll
            for (int jn = 0; jn < 4; ++jn) {
                const int col = nt * 128 + wn * 64 + jn * 16 + (lane & 15);
                yrow[col] = acc[i][jn][r];
            }
        }
    }
}

// ---------------------------------------------------------------------------
// Combine: out[t] = w0*y[row0] + w1*y[row1]   (fully overwrites d_out)
// ---------------------------------------------------------------------------
__global__ __launch_bounds__(256) void combine_kernel(const float* __restrict__ yb,
                                                      const int* __restrict__ s2r,
                                                      const float* __restrict__ tkw,
                                                      float* __restrict__ out) {
    const int idx = blockIdx.x * 256 + threadIdx.x;   // one float4 per thread
    const int t = idx >> 8;                           // 256 float4 per token
    const int c = (idx & 255) * 4;
    const int r0 = s2r[t * 2], r1 = s2r[t * 2 + 1];
    const float w0 = tkw[t * 2], w1 = tkw[t * 2 + 1];
    const float4 a = *(const float4*)(yb + (size_t)r0 * D_DIM + c);
    const float4 b = *(const float4*)(yb + (size_t)r1 * D_DIM + c);
    float4 o;
    o.x = w0 * a.x + w1 * b.x;
    o.y = w0 * a.y + w1 * b.y;
    o.z = w0 * a.z + w1 * b.z;
    o.w = w0 * a.w + w1 * b.w;
    *(float4*)(out + (size_t)t * D_DIM + c) = o;
}

// ---------------------------------------------------------------------------
extern "C" void kernel_launch(void* const* d_in, const int* in_sizes, int n_in,
                              void* d_out, int out_size, void* d_ws, size_t ws_size,
                              hipStream_t stream) {
    const float* x  = (const float*)d_in[0];
    const float* gw = (const float*)d_in[1];
    const float* w1 = (const float*)d_in[2];
    const float* w3 = (const float*)d_in[3];
    const float* w2 = (const float*)d_in[4];
    float* out = (float*)d_out;

    char* ws = (char*)d_ws;
    // [0, 134.2MB)            wb13t [E][2F][D] bf16 (w1/w3 interleaved, dead after gemm1)
    //   alias [0, 67.1MB)     wb2t  [E][D][F]  bf16 (built after gemm1)
    //   alias [67.1, 138.4MB) yb    [RCAP][D]  fp32 (written by gemm2; overlaps dead
    //                                               wb13t tail + dead xp head)
    // [134.2, 169.9MB)        xp    [RCAP][D]  bf16 (dead after gemm1)
    // [169.9, 312.5MB)        hb    [RCAP][F]  bf16
    bf16*  wb13t = (bf16*)(ws);
    bf16*  wb2t  = (bf16*)(ws);
    float* yb    = (float*)(ws + (size_t)67108864);
    bf16*  xp    = (bf16*)(ws + (size_t)134217728);
    size_t off   = (size_t)134217728 + (size_t)RCAP * D_DIM * 2;
    bf16*  hb    = (bf16*)(ws + off); off += (size_t)RCAP * F_DIM * 2;
    int*   tki = (int*)(ws + off);   off += (size_t)T_TOK * 2 * 4;
    float* tkw = (float*)(ws + off); off += (size_t)T_TOK * 2 * 4;
    int* counts = (int*)(ws + off);  off += 64;
    int* cursor = (int*)(ws + off);  off += 64;
    int* aoff   = (int*)(ws + off);  off += 64;
    int* s2r    = (int*)(ws + off);  off += (size_t)T_TOK * 2 * 4;

    hipMemsetAsync(counts, 0, 64, stream);

    gate_kernel<<<T_TOK / 4, 256, 0, stream>>>(x, gw, tki, tkw, counts);
    scan_kernel<<<1, 64, 0, stream>>>(counts, aoff, cursor);
    gather_kernel<<<(T_TOK * 2) / 4, 256, 0, stream>>>(x, tki, cursor, s2r, xp);

    trans_kernel<<<dim3(F_DIM / 64, D_DIM / 64, E_NUM), 256, 0, stream>>>(w1, wb13t, D_DIM, F_DIM, 1);
    trans_kernel<<<dim3(F_DIM / 64, D_DIM / 64, E_NUM), 256, 0, stream>>>(w3, wb13t, D_DIM, F_DIM, 2);

    // grid.y = 72 >= sum_e ceil(counts[e]/256) (16384/256 + 8)
    gemm1_kernel<<<dim3(2 * F_DIM / 256, 72), 512, 0, stream>>>(xp, wb13t, hb, aoff, counts);

    trans_kernel<<<dim3(D_DIM / 64, F_DIM / 64, E_NUM), 256, 0, stream>>>(w2, wb2t, F_DIM, D_DIM, 0);

    gemm2_kernel<<<dim3(D_DIM / 128, MT), 256, 0, stream>>>(hb, wb2t, yb, aoff, counts);

    combine_kernel<<<(T_TOK * 256) / 256, 256, 0, stream>>>(yb, s2r, tkw, out);
}

// Round 3
// 1345.370 us; speedup vs baseline: 1.0497x; 1.0345x over previous
//
#include <hip/hip_runtime.h>
#include <stdint.h>

#define T_TOK 8192
#define D_DIM 1024
#define F_DIM 4096
#define E_NUM 8
#define RCAP  17408   // 136 * 128 >= 16384 + 8*127 (per-expert 128-aligned regions)
#define MT    136

typedef __bf16 bf16;
typedef __bf16 bf16x8 __attribute__((ext_vector_type(8)));
typedef float  f32x4  __attribute__((ext_vector_type(4)));

typedef const __attribute__((address_space(1))) void* gptr1;
typedef __attribute__((address_space(3))) void* lptr3;

__device__ __forceinline__ void gload_lds16(const void* g, void* l) {
    // async global->LDS DMA, 16B/lane; LDS dest = wave-uniform base + lane*16
    __builtin_amdgcn_global_load_lds((gptr1)g, (lptr3)l, 16, 0, 0);
}

__device__ __forceinline__ unsigned short f2b(float f) {
    // fp32 -> bf16 round-to-nearest-even
    uint32_t u = __float_as_uint(f);
    u = (u + 0x7FFFu + ((u >> 16) & 1u)) >> 16;
    return (unsigned short)u;
}

// ---------------------------------------------------------------------------
// Transpose-convert: src fp32 [E][R][C] -> dst bf16.
//   mode 0: dst [E][C][R]            (plain B^T, used for w2)
//   mode 1: dst [E][2C][R], col f -> row (f>>5)*64 +      (f&31)   (w1 slots)
//   mode 2: dst [E][2C][R], col f -> row (f>>5)*64 + 32 + (f&31)   (w3 slots)
// LDS scheme: stage fp32 tile UN-transposed [64][68] (stride 272B, 16B-aligned,
// b128 writes conflict-free); transpose on the read side (b32 scalar reads,
// <=4-way).
// ---------------------------------------------------------------------------
__global__ __launch_bounds__(256) void trans_kernel(const float* __restrict__ src,
                                                    bf16* __restrict__ dst,
                                                    int R, int C, int mode) {
    __shared__ float lt[64 * 68];
    const int e  = blockIdx.z;
    const int c0 = blockIdx.x * 64;
    const int r0 = blockIdx.y * 64;
    const float* s = src + (size_t)e * R * C;
    unsigned short* dp = (unsigned short*)dst + (size_t)e * R * C * (mode ? 2 : 1);
    const int t  = threadIdx.x;
    const int tr = t >> 4;
    const int tc = (t & 15) * 4;
    #pragma unroll
    for (int rr = 0; rr < 4; ++rr) {
        const int r = tr + rr * 16;
        const float4 v = *(const float4*)(s + (size_t)(r0 + r) * C + c0 + tc);
        *(float4*)&lt[r * 68 + tc] = v;
    }
    __syncthreads();
    const int oc  = t >> 2;           // 0..63: logical output column f
    const int seg = (t & 3) * 16;     // 16-element segment along R
    __attribute__((aligned(16))) unsigned short ob[16];
    #pragma unroll
    for (int i = 0; i < 16; ++i) ob[i] = f2b(lt[(seg + i) * 68 + oc]);
    const int f  = c0 + oc;
    const int fr = mode ? ((f >> 5) * 64 + ((mode == 2) ? 32 : 0) + (f & 31)) : f;
    unsigned short* orow = dp + (size_t)fr * R + (r0 + seg);
    *(uint4*)(orow)     = *(const uint4*)&ob[0];
    *(uint4*)(orow + 8) = *(const uint4*)&ob[8];
}

// ---------------------------------------------------------------------------
// Gate: fp32 logits (wave per token), top-2, softmax, per-expert counts
// ---------------------------------------------------------------------------
__global__ __launch_bounds__(256) void gate_kernel(const float* __restrict__ x,
                                                   const float* __restrict__ gw,
                                                   int* __restrict__ tki,
                                                   float* __restrict__ tkw,
                                                   int* __restrict__ counts) {
    const int t    = blockIdx.x * 4 + (threadIdx.x >> 6);
    const int lane = threadIdx.x & 63;
    const float* xr = x + (size_t)t * D_DIM;
    float acc[E_NUM];
    #pragma unroll
    for (int e = 0; e < E_NUM; ++e) acc[e] = 0.f;
    for (int j = 0; j < 16; ++j) {
        const int d = lane + 64 * j;
        const float xv = xr[d];
        const float* g = gw + (size_t)d * E_NUM;
        #pragma unroll
        for (int e = 0; e < E_NUM; ++e) acc[e] += xv * g[e];
    }
    #pragma unroll
    for (int off = 32; off >= 1; off >>= 1) {
        #pragma unroll
        for (int e = 0; e < E_NUM; ++e) acc[e] += __shfl_xor(acc[e], off);
    }
    if (lane == 0) {
        int b0 = 0; float v0 = acc[0];
        #pragma unroll
        for (int e = 1; e < E_NUM; ++e) if (acc[e] > v0) { v0 = acc[e]; b0 = e; }
        int b1 = -1; float v1 = -1e30f;
        #pragma unroll
        for (int e = 0; e < E_NUM; ++e) if (e != b0 && acc[e] > v1) { v1 = acc[e]; b1 = e; }
        const float ex = expf(v1 - v0);           // v1 <= v0
        const float w0 = 1.f / (1.f + ex);
        const float w1 = ex * w0;
        tki[t * 2]     = b0;  tkw[t * 2]     = w0;
        tki[t * 2 + 1] = b1;  tkw[t * 2 + 1] = w1;
        atomicAdd(&counts[b0], 1);
        atomicAdd(&counts[b1], 1);
    }
}

// ---------------------------------------------------------------------------
// Scan: 128-aligned exclusive offsets per expert
// ---------------------------------------------------------------------------
__global__ void scan_kernel(const int* __restrict__ counts, int* __restrict__ aoff,
                            int* __restrict__ cursor) {
    if (threadIdx.x == 0) {
        int off = 0;
        #pragma unroll
        for (int e = 0; e < E_NUM; ++e) {
            aoff[e]   = off;
            cursor[e] = off;
            off += (counts[e] + 127) & ~127;
        }
        aoff[E_NUM] = off;
    }
}

// ---------------------------------------------------------------------------
// Gather: assign permuted rows, record slot->row, convert x rows to bf16
// ---------------------------------------------------------------------------
__global__ __launch_bounds__(256) void gather_kernel(const float* __restrict__ x,
                                                     const int* __restrict__ tki,
                                                     int* __restrict__ cursor,
                                                     int* __restrict__ s2r,
                                                     bf16* __restrict__ xp) {
    const int slot = blockIdx.x * 4 + (threadIdx.x >> 6);
    const int lane = threadIdx.x & 63;
    const int t = slot >> 1;
    int row = 0;
    if (lane == 0) {
        const int e = tki[slot];
        row = atomicAdd(&cursor[e], 1);
        s2r[slot] = row;
    }
    row = __shfl(row, 0);
    const float* xr = x + (size_t)t * D_DIM + lane * 16;
    unsigned short* dst = (unsigned short*)xp + (size_t)row * D_DIM + lane * 16;
    uint32_t u[8];
    #pragma unroll
    for (int q = 0; q < 4; ++q) {
        const float4 v = *(const float4*)(xr + q * 4);
        u[q * 2]     = (uint32_t)f2b(v.x) | ((uint32_t)f2b(v.y) << 16);
        u[q * 2 + 1] = (uint32_t)f2b(v.z) | ((uint32_t)f2b(v.w) << 16);
    }
    ((uint4*)dst)[0] = make_uint4(u[0], u[1], u[2], u[3]);
    ((uint4*)dst)[1] = make_uint4(u[4], u[5], u[6], u[7]);
}

// ---------------------------------------------------------------------------
// GEMM1: fused SwiGLU, 256x256x64 phase-pipelined (T2+T3+T4+T5 template).
//   R3: REVERTED to natural mapping (nt=blockIdx.x, bm=blockIdx.y).
//   HW dispatch gives XCD = nt%8: each XCD runs {4 nt x 8 bm} concurrently ->
//   B working set 2MB (L2-cached across bm), A panels shared by 4 nt.
//   R2's bm-chunk swizzle measured 2.3x FETCH (575MB vs 251MB) and +32us:
//   it serialized 32 distinct B panels (16.8MB) through the 4MB L2 per bm.
// ---------------------------------------------------------------------------
__global__ __launch_bounds__(512, 2) void gemm1_kernel(const bf16* __restrict__ xp,
                                                       const bf16* __restrict__ wb13t,
                                                       bf16* __restrict__ hb,
                                                       const int* __restrict__ aoff,
                                                       const int* __restrict__ counts) {
    __shared__ __align__(16) char As[65536];
    __shared__ __align__(16) char Bs[65536];

    const int nt = blockIdx.x;
    int bm = blockIdx.y;
    int e  = 0;
    for (; e < E_NUM; ++e) {
        const int nbi = (counts[e] + 255) >> 8;
        if (bm < nbi) break;
        bm -= nbi;
    }
    if (e >= E_NUM) return;
    const int m_base = aoff[e] + bm * 256;
    const int row_hi = aoff[e + 1];          // store mask: don't stomp next expert

    const int tid  = threadIdx.x;
    const int w    = tid >> 6;               // 0..7
    const int lane = tid & 63;
    const int wm   = w >> 2;                 // 0..1 (M half)
    const int wn   = w & 3;                  // 0..3 (N quarter)

    // ---- staging constants (linear LDS dest; swizzle folded into global col)
    const int    lsub = lane >> 3;                                // 0..7
    const size_t swz  = (size_t)(((lane & 7) ^ lsub) << 3);       // elems
    const bf16* Ag = xp    + (size_t)m_base * D_DIM;
    const bf16* Bg = wb13t + ((size_t)e * (2 * F_DIM) + (size_t)nt * 256) * D_DIM;
    char* sAd = As + w * 2048 + lane * 16;   // + c*32768 + h*16384 + j*1024
    char* sBd = Bs + w * 2048 + lane * 16;
    const int rst = w * 16 + lsub;           // staging row base (j adds 8, h adds 128)

#define G1_STAGE_A(cc, kt, h)                                                         \
    do {                                                                              \
        const size_t kcol = (size_t)(kt) * 64 + swz;                                  \
        gload_lds16(Ag + (size_t)((h) * 128 + rst) * D_DIM + kcol,                    \
                    sAd + (cc) * 32768 + (h) * 16384);                                \
        gload_lds16(Ag + (size_t)((h) * 128 + rst + 8) * D_DIM + kcol,                \
                    sAd + (cc) * 32768 + (h) * 16384 + 1024);                         \
    } while (0)
#define G1_STAGE_B(cc, kt, h)                                                         \
    do {                                                                              \
        const size_t kcol = (size_t)(kt) * 64 + swz;                                  \
        gload_lds16(Bg + (size_t)((h) * 128 + rst) * D_DIM + kcol,                    \
                    sBd + (cc) * 32768 + (h) * 16384);                                \
        gload_lds16(Bg + (size_t)((h) * 128 + rst + 8) * D_DIM + kcol,                \
                    sBd + (cc) * 32768 + (h) * 16384 + 1024);                         \
    } while (0)

    // ---- fragment read constants (swizzled): row&7 == fm&7 for all frags
    const int fm  = lane & 15;
    const int kq  = lane >> 4;                                  // 0..3
    const int kg0 = ((kq       ^ (fm & 7)) << 4);               // ks=0 byte slot
    const int kg1 = (((4 | kq) ^ (fm & 7)) << 4);               // ks=1 byte slot
    const char* Arb = As + wm * 16384 + fm * 128;
    const char* Brb = Bs + (wn >> 1) * 16384 + ((wn & 1) * 64 + fm) * 128;

    f32x4 acc[8][4] = {};
    bf16x8 aF[4][2], b0F[2][2], b1F[2][2];

    // ---- prologue: A(0),B(0) -> buf0 ; B(1) -> buf1 ; wait tile0 only
    G1_STAGE_A(0, 0, 0); G1_STAGE_A(0, 0, 1);
    G1_STAGE_B(0, 0, 0); G1_STAGE_B(0, 0, 1);
    G1_STAGE_B(1, 1, 0); G1_STAGE_B(1, 1, 1);
    asm volatile("s_waitcnt vmcnt(4)" ::: "memory");
    __builtin_amdgcn_s_barrier();
    __builtin_amdgcn_sched_barrier(0);

    for (int u = 0; u < D_DIM / 64; ++u) {
        const int c = u & 1;
        const char* Ar = Arb + c * 32768;
        const char* Br = Brb + c * 32768;

        // ======== phase 0: read A(mh0)+B(nh0); stage A-h0(u+1); MFMA q(0,0)
        #pragma unroll
        for (int i = 0; i < 4; ++i) {
            aF[i][0] = *(const bf16x8*)(Ar + i * 2048 + kg0);
            aF[i][1] = *(const bf16x8*)(Ar + i * 2048 + kg1);
        }
        #pragma unroll
        for (int j = 0; j < 2; ++j) {
            b0F[j][0] = *(const bf16x8*)(Br + j * 2048 + kg0);
            b0F[j][1] = *(const bf16x8*)(Br + j * 2048 + kg1);
        }
        if (u + 1 < D_DIM / 64) G1_STAGE_A(c ^ 1, u + 1, 0);
        __builtin_amdgcn_s_barrier();
        asm volatile("s_waitcnt lgkmcnt(0)" ::: "memory");
        __builtin_amdgcn_s_setprio(1);
        #pragma unroll
        for (int i = 0; i < 4; ++i)
            #pragma unroll
            for (int j = 0; j < 2; ++j) {
                acc[i][j] = __builtin_amdgcn_mfma_f32_16x16x32_bf16(aF[i][0], b0F[j][0], acc[i][j], 0, 0, 0);
                acc[i][j] = __builtin_amdgcn_mfma_f32_16x16x32_bf16(aF[i][1], b0F[j][1], acc[i][j], 0, 0, 0);
            }
        __builtin_amdgcn_s_setprio(0);
        __builtin_amdgcn_s_barrier();

        // ======== phase 1: read B(nh1); stage A-h1(u+1); MFMA q(0,1)
        #pragma unroll
        for (int j = 0; j < 2; ++j) {
            b1F[j][0] = *(const bf16x8*)(Br + (j + 2) * 2048 + kg0);
            b1F[j][1] = *(const bf16x8*)(Br + (j + 2) * 2048 + kg1);
        }
        if (u + 1 < D_DIM / 64) G1_STAGE_A(c ^ 1, u + 1, 1);
        __builtin_amdgcn_s_barrier();
        asm volatile("s_waitcnt lgkmcnt(0)" ::: "memory");
        __builtin_amdgcn_s_setprio(1);
        #pragma unroll
        for (int i = 0; i < 4; ++i)
            #pragma unroll
            for (int j = 0; j < 2; ++j) {
                acc[i][j + 2] = __builtin_amdgcn_mfma_f32_16x16x32_bf16(aF[i][0], b1F[j][0], acc[i][j + 2], 0, 0, 0);
                acc[i][j + 2] = __builtin_amdgcn_mfma_f32_16x16x32_bf16(aF[i][1], b1F[j][1], acc[i][j + 2], 0, 0, 0);
            }
        __builtin_amdgcn_s_setprio(0);
        __builtin_amdgcn_s_barrier();

        // ======== phase 2: read A(mh1); stage B-h0(u+2) (released after p1); MFMA q(1,0)
        #pragma unroll
        for (int i = 0; i < 4; ++i) {
            aF[i][0] = *(const bf16x8*)(Ar + (i + 4) * 2048 + kg0);
            aF[i][1] = *(const bf16x8*)(Ar + (i + 4) * 2048 + kg1);
        }
        if (u + 2 < D_DIM / 64) G1_STAGE_B(c, u + 2, 0);
        __builtin_amdgcn_s_barrier();
        asm volatile("s_waitcnt lgkmcnt(0)" ::: "memory");
        __builtin_amdgcn_s_setprio(1);
        #pragma unroll
        for (int i = 0; i < 4; ++i)
            #pragma unroll
            for (int j = 0; j < 2; ++j) {
                acc[i + 4][j] = __builtin_amdgcn_mfma_f32_16x16x32_bf16(aF[i][0], b0F[j][0], acc[i + 4][j], 0, 0, 0);
                acc[i + 4][j] = __builtin_amdgcn_mfma_f32_16x16x32_bf16(aF[i][1], b0F[j][1], acc[i + 4][j], 0, 0, 0);
            }
        __builtin_amdgcn_s_setprio(0);
        __builtin_amdgcn_s_barrier();

        // ======== phase 3: stage B-h1(u+2); MFMA q(1,1) (operands already in regs)
        if (u + 2 < D_DIM / 64) G1_STAGE_B(c, u + 2, 1);
        __builtin_amdgcn_s_setprio(1);
        #pragma unroll
        for (int i = 0; i < 4; ++i)
            #pragma unroll
            for (int j = 0; j < 2; ++j) {
                acc[i + 4][j + 2] = __builtin_amdgcn_mfma_f32_16x16x32_bf16(aF[i][0], b1F[j][0], acc[i + 4][j + 2], 0, 0, 0);
                acc[i + 4][j + 2] = __builtin_amdgcn_mfma_f32_16x16x32_bf16(aF[i][1], b1F[j][1], acc[i + 4][j + 2], 0, 0, 0);
            }
        __builtin_amdgcn_s_setprio(0);

        // ======== tile boundary: counted wait (A(u+1)&B(u+1) done; B(u+2) in flight)
        if (u == D_DIM / 64 - 1) break;
        if (u + 2 < D_DIM / 64) {
            asm volatile("s_waitcnt vmcnt(4)" ::: "memory");
        } else {
            asm volatile("s_waitcnt vmcnt(0)" ::: "memory");
        }
        __builtin_amdgcn_s_barrier();
        __builtin_amdgcn_sched_barrier(0);
    }

    // ---- epilogue: silu(s1)*s3 -> bf16  (C/D: col=lane&15, row=(lane>>4)*4+reg)
    unsigned short* hw = (unsigned short*)hb;
    const int g    = nt * 4 + wn;                 // 32-col h group
    const int colb = g * 32 + fm;
    const int rb0  = m_base + wm * 128 + (kq << 2);
    #pragma unroll
    for (int i = 0; i < 8; ++i) {
        #pragma unroll
        for (int r = 0; r < 4; ++r) {
            const int row = rb0 + i * 16 + r;
            if (row < row_hi) {
                #pragma unroll
                for (int jj = 0; jj < 2; ++jj) {
                    const float s1 = acc[i][jj][r];
                    const float s3 = acc[i][jj + 2][r];
                    const float hv = (s1 / (1.0f + __expf(-s1))) * s3;
                    hw[(size_t)row * F_DIM + colb + jj * 16] = f2b(hv);
                }
            }
        }
    }
#undef G1_STAGE_A
#undef G1_STAGE_B
}

// ---------------------------------------------------------------------------
// GEMM2: y = H @ W2 (per permuted row, fp32 out, no atomics)
//   R3: BK 32 -> 64.  Halves barrier count (64 K-iters instead of 128),
//   32 MFMA per sync.  LDS 2 x [128][64] bf16 = 32KB.  Staging uses gemm1's
//   row&7 XOR swizzle (8 16B-slots per 128B row), conflict-free ds_read_b128.
//   Keeps R2's XCD-chunk swizzle (A panels read once per XCD; wb2t 67MB is
//   LLC-resident so B re-reads stay cheap).
// ---------------------------------------------------------------------------
__global__ __launch_bounds__(256, 2) void gemm2_kernel(const bf16* __restrict__ hb,
                                                       const bf16* __restrict__ wb2t,
                                                       float* __restrict__ yb,
                                                       const int* __restrict__ aoff,
                                                       const int* __restrict__ counts) {
    __shared__ __align__(16) bf16 As[128 * 64];
    __shared__ __align__(16) bf16 Bs[128 * 64];

    // grid = (8, 136) -> flat in [0,1088), 1088/8 = 136.
    const int flat    = blockIdx.y * 8 + blockIdx.x;
    const int logical = (flat & 7) * 136 + (flat >> 3);
    const int nt      = logical & 7;
    const int m_base  = (logical >> 3) * 128;

    int e = 0;
    #pragma unroll
    for (int i = 1; i < E_NUM; ++i) if (m_base >= aoff[i]) e = i;
    if (m_base - aoff[e] >= counts[e]) return;

    const int tid  = threadIdx.x;
    const int w    = tid >> 6;               // 0..3
    const int lane = tid & 63;
    const int wm   = w & 1, wn = w >> 1;

    const bf16* Ab = hb + (size_t)m_base * F_DIM;
    const bf16* Bb = wb2t + ((size_t)e * D_DIM + (size_t)nt * 128) * F_DIM;

    // staging: wave stages 32 rows (w*32 + j*8 + lsub), 8 rows per gload pair
    const int lsub = lane >> 3;                        // 0..7
    const int swzc = ((lane & 7) ^ lsub) * 8;          // swizzled global col (elems)
    const int rst  = w * 32 + lsub;                    // + j*8
    // LDS dest: wave-uniform base (HW adds lane*16B): row w*32+j*8+(lane>>3),
    // 16B slot lane&7  ->  elem offset w*2048 + j*512
    bf16* sAd = As + w * 2048;
    bf16* sBd = Bs + w * 2048;

    // fragment reads: row&7 == fm&7; slot = (ks*4+kq) ^ (fm&7)
    const int fm  = lane & 15;
    const int kq  = lane >> 4;                         // 0..3
    const int sl0 = ((kq    ) ^ (fm & 7)) * 8;         // elems (ks=0)
    const int sl1 = ((kq | 4) ^ (fm & 7)) * 8;         // elems (ks=1)

    f32x4 acc[4][4] = {};

    for (int kt = 0; kt < F_DIM / 64; ++kt) {
        const int k0 = kt * 64;
        #pragma unroll
        for (int j = 0; j < 4; ++j) {
            gload_lds16(Ab + (size_t)(rst + j * 8) * F_DIM + (k0 + swzc), sAd + j * 512);
            gload_lds16(Bb + (size_t)(rst + j * 8) * F_DIM + (k0 + swzc), sBd + j * 512);
        }
        __syncthreads();
        bf16x8 af[4][2], bfr[4][2];
        #pragma unroll
        for (int i = 0; i < 4; ++i) {
            const int ar = (wm * 64 + i * 16 + fm) * 64;
            const int br = (wn * 64 + i * 16 + fm) * 64;
            af[i][0]  = *(const bf16x8*)&As[ar + sl0];
            af[i][1]  = *(const bf16x8*)&As[ar + sl1];
            bfr[i][0] = *(const bf16x8*)&Bs[br + sl0];
            bfr[i][1] = *(const bf16x8*)&Bs[br + sl1];
        }
        #pragma unroll
        for (int i = 0; i < 4; ++i) {
            #pragma unroll
            for (int jn = 0; jn < 4; ++jn) {
                acc[i][jn] = __builtin_amdgcn_mfma_f32_16x16x32_bf16(af[i][0], bfr[jn][0], acc[i][jn], 0, 0, 0);
                acc[i][jn] = __builtin_amdgcn_mfma_f32_16x16x32_bf16(af[i][1], bfr[jn][1], acc[i][jn], 0, 0, 0);
            }
        }
        __syncthreads();
    }

    #pragma unroll
    for (int i = 0; i < 4; ++i) {
        const int rb = m_base + wm * 64 + i * 16 + (lane >> 4) * 4;
        #pragma unroll
        for (int r = 0; r < 4; ++r) {
            float* yrow = yb + (size_t)(rb + r) * D_DIM;
            #pragma unroll
            for (int jn = 0; jn < 4; ++jn) {
                const int col = nt * 128 + wn * 64 + jn * 16 + (lane & 15);
                yrow[col] = acc[i][jn][r];
            }
        }
    }
}

// ---------------------------------------------------------------------------
// Combine: out[t] = w0*y[row0] + w1*y[row1]   (fully overwrites d_out)
// ---------------------------------------------------------------------------
__global__ __launch_bounds__(256) void combine_kernel(const float* __restrict__ yb,
                                                      const int* __restrict__ s2r,
                                                      const float* __restrict__ tkw,
                                                      float* __restrict__ out) {
    const int idx = blockIdx.x * 256 + threadIdx.x;   // one float4 per thread
    const int t = idx >> 8;                           // 256 float4 per token
    const int c = (idx & 255) * 4;
    const int r0 = s2r[t * 2], r1 = s2r[t * 2 + 1];
    const float w0 = tkw[t * 2], w1 = tkw[t * 2 + 1];
    const float4 a = *(const float4*)(yb + (size_t)r0 * D_DIM + c);
    const float4 b = *(const float4*)(yb + (size_t)r1 * D_DIM + c);
    float4 o;
    o.x = w0 * a.x + w1 * b.x;
    o.y = w0 * a.y + w1 * b.y;
    o.z = w0 * a.z + w1 * b.z;
    o.w = w0 * a.w + w1 * b.w;
    *(float4*)(out + (size_t)t * D_DIM + c) = o;
}

// ---------------------------------------------------------------------------
extern "C" void kernel_launch(void* const* d_in, const int* in_sizes, int n_in,
                              void* d_out, int out_size, void* d_ws, size_t ws_size,
                              hipStream_t stream) {
    const float* x  = (const float*)d_in[0];
    const float* gw = (const float*)d_in[1];
    const float* w1 = (const float*)d_in[2];
    const float* w3 = (const float*)d_in[3];
    const float* w2 = (const float*)d_in[4];
    float* out = (float*)d_out;

    char* ws = (char*)d_ws;
    // [0, 134.2MB)            wb13t [E][2F][D] bf16 (w1/w3 interleaved, dead after gemm1)
    //   alias [0, 67.1MB)     wb2t  [E][D][F]  bf16 (built after gemm1)
    //   alias [67.1, 138.4MB) yb    [RCAP][D]  fp32 (written by gemm2; overlaps dead
    //                                               wb13t tail + dead xp head)
    // [134.2, 169.9MB)        xp    [RCAP][D]  bf16 (dead after gemm1)
    // [169.9, 312.5MB)        hb    [RCAP][F]  bf16
    bf16*  wb13t = (bf16*)(ws);
    bf16*  wb2t  = (bf16*)(ws);
    float* yb    = (float*)(ws + (size_t)67108864);
    bf16*  xp    = (bf16*)(ws + (size_t)134217728);
    size_t off   = (size_t)134217728 + (size_t)RCAP * D_DIM * 2;
    bf16*  hb    = (bf16*)(ws + off); off += (size_t)RCAP * F_DIM * 2;
    int*   tki = (int*)(ws + off);   off += (size_t)T_TOK * 2 * 4;
    float* tkw = (float*)(ws + off); off += (size_t)T_TOK * 2 * 4;
    int* counts = (int*)(ws + off);  off += 64;
    int* cursor = (int*)(ws + off);  off += 64;
    int* aoff   = (int*)(ws + off);  off += 64;
    int* s2r    = (int*)(ws + off);  off += (size_t)T_TOK * 2 * 4;

    hipMemsetAsync(counts, 0, 64, stream);

    gate_kernel<<<T_TOK / 4, 256, 0, stream>>>(x, gw, tki, tkw, counts);
    scan_kernel<<<1, 64, 0, stream>>>(counts, aoff, cursor);
    gather_kernel<<<(T_TOK * 2) / 4, 256, 0, stream>>>(x, tki, cursor, s2r, xp);

    trans_kernel<<<dim3(F_DIM / 64, D_DIM / 64, E_NUM), 256, 0, stream>>>(w1, wb13t, D_DIM, F_DIM, 1);
    trans_kernel<<<dim3(F_DIM / 64, D_DIM / 64, E_NUM), 256, 0, stream>>>(w3, wb13t, D_DIM, F_DIM, 2);

    // grid.y = 72 >= sum_e ceil(counts[e]/256) (16384/256 + 8)
    gemm1_kernel<<<dim3(2 * F_DIM / 256, 72), 512, 0, stream>>>(xp, wb13t, hb, aoff, counts);

    trans_kernel<<<dim3(D_DIM / 64, F_DIM / 64, E_NUM), 256, 0, stream>>>(w2, wb2t, F_DIM, D_DIM, 0);

    gemm2_kernel<<<dim3(D_DIM / 128, MT), 256, 0, stream>>>(hb, wb2t, yb, aoff, counts);

    combine_kernel<<<(T_TOK * 256) / 256, 256, 0, stream>>>(yb, s2r, tkw, out);
}